// Round 1
// 144.265 us; speedup vs baseline: 1.0547x; 1.0547x over previous
//
#include <hip/hip_runtime.h>

#define BB 4
#define NN 4096
#define CC 128
#define NROWS (BB * NN)   // 16384 rows per tensor

// workspace layout (float offsets)
#define QN_OFF  0                              // |q_proj| per row (16384)
#define QP_OFF  (QN_OFF + NROWS)               // projected q, 16384 x 128
#define MM_OFF  (QP_OFF + NROWS * CC)          // B x 128 x 128  M = M0 W^T + Ksum b^T
#define KS_OFF  (MM_OFF + BB * CC * CC)        // B x 128  Ksum (sum of khat rows)
#define PP_OFF  (KS_OFF + BB * CC)             // 512 x 16384 partial M0s
#define KP_OFF  (PP_OFF + 512 * CC * CC)       // 512 x 128 partial ksums

// ---------------------------------------------------------------------------
// Kernel 1: symmetric fused projection + partial-M build.
// Every block: project 32 q rows (store q_proj + norms) and 32 k rows
// (normalize into LDS), then build a rank-32 partial M0 + partial ksum.
// All 512 blocks do identical work -> sustained 2 blocks/CU, no tail.
// ---------------------------------------------------------------------------
__global__ __launch_bounds__(256, 2) void projpb_kernel(
    const float* __restrict__ q_node, const float* __restrict__ k_node,
    const float* __restrict__ v_node, const float* __restrict__ W,
    const float* __restrict__ bias, float* __restrict__ ws)
{
    __shared__ float S[CC * CC];    // phase 1: swizzled W^T; phase 2: khat|v tiles
    __shared__ float4 red[256];
    const int tid = threadIdx.x;

    for (int e = tid; e < CC * CC; e += 256) {
        int d = e >> 7, c = e & 127;
        S[(c << 7) + ((((d >> 2) ^ (c & 31)) << 2) | (d & 3))] = W[e];
    }

    const int blk  = blockIdx.x;        // 0..511
    const int base = blk * 32;          // row base (same rows in q and k tensors)
    const int dg = tid & 31;
    const int rg = tid >> 5;

    float4 bias4 = ((const float4*)bias)[dg];
    float4 acc[8];
#pragma unroll
    for (int i = 0; i < 8; i++) acc[i] = bias4;

    __syncthreads();

    const float4* Qv = (const float4*)(q_node + (size_t)(base + rg * 4) * CC);
    const float4* Kv = (const float4*)(k_node + (size_t)(base + rg * 4) * CC);

    for (int c = 0; c < CC; c += 4) {
        const int c4 = c >> 2;
        float4 w0 = ((const float4*)S)[((c + 0) << 5) + (dg ^ ((c + 0) & 31))];
        float4 w1 = ((const float4*)S)[((c + 1) << 5) + (dg ^ ((c + 1) & 31))];
        float4 w2 = ((const float4*)S)[((c + 2) << 5) + (dg ^ ((c + 2) & 31))];
        float4 w3 = ((const float4*)S)[((c + 3) << 5) + (dg ^ ((c + 3) & 31))];
#pragma unroll
        for (int i = 0; i < 4; i++) {
            float4 x = Qv[i * 32 + c4];
            acc[i].x += x.x * w0.x + x.y * w1.x + x.z * w2.x + x.w * w3.x;
            acc[i].y += x.x * w0.y + x.y * w1.y + x.z * w2.y + x.w * w3.y;
            acc[i].z += x.x * w0.z + x.y * w1.z + x.z * w2.z + x.w * w3.z;
            acc[i].w += x.x * w0.w + x.y * w1.w + x.z * w2.w + x.w * w3.w;
            float4 y = Kv[i * 32 + c4];
            acc[4 + i].x += y.x * w0.x + y.y * w1.x + y.z * w2.x + y.w * w3.x;
            acc[4 + i].y += y.x * w0.y + y.y * w1.y + y.z * w2.y + y.w * w3.y;
            acc[4 + i].z += y.x * w0.z + y.y * w1.z + y.z * w2.z + y.w * w3.z;
            acc[4 + i].w += y.x * w0.w + y.y * w1.w + y.z * w2.w + y.w * w3.w;
        }
    }

    // q rows: store projected row + norm
#pragma unroll
    for (int i = 0; i < 4; i++) {
        const int rq = base + rg * 4 + i;
        float ss = acc[i].x * acc[i].x + acc[i].y * acc[i].y
                 + acc[i].z * acc[i].z + acc[i].w * acc[i].w;
#pragma unroll
        for (int off = 16; off > 0; off >>= 1) ss += __shfl_xor(ss, off, 32);
        ((float4*)(ws + QP_OFF + (size_t)rq * CC))[dg] = acc[i];
        if (dg == 0) ws[QN_OFF + rq] = sqrtf(ss);
    }

    __syncthreads();   // everyone done reading W before LDS reuse

    float* Khs = S;            // 32 x 128 (16 KB)
    float* Vs  = S + 4096;     // 32 x 128 (16 KB)

    // k rows: normalize into LDS
#pragma unroll
    for (int i = 0; i < 4; i++) {
        float ss = acc[4 + i].x * acc[4 + i].x + acc[4 + i].y * acc[4 + i].y
                 + acc[4 + i].z * acc[4 + i].z + acc[4 + i].w * acc[4 + i].w;
#pragma unroll
        for (int off = 16; off > 0; off >>= 1) ss += __shfl_xor(ss, off, 32);
        float inv = 1.0f / sqrtf(ss);
        float4 o = acc[4 + i];
        o.x *= inv; o.y *= inv; o.z *= inv; o.w *= inv;
        ((float4*)(Khs + (rg * 4 + i) * CC))[dg] = o;
    }

    // stage v rows 32x128
    const int c4 = tid & 31, nr = tid >> 5;
    const float* Vp = v_node + (size_t)base * CC;
#pragma unroll
    for (int i = 0; i < 4; i++) {
        int n = nr + i * 8;
        ((float4*)(Vs + n * CC))[c4] = ((const float4*)(Vp + (size_t)n * CC))[c4];
    }
    __syncthreads();

    float4 ksum4 = make_float4(0.f, 0.f, 0.f, 0.f);
#pragma unroll
    for (int i = 0; i < 4; i++) {
        int n = nr + i * 8;
        float4 kv = ((const float4*)(Khs + n * CC))[c4];
        ksum4.x += kv.x; ksum4.y += kv.y; ksum4.z += kv.z; ksum4.w += kv.w;
    }

    const int dg2 = tid & 15, cg = tid >> 4;
    float a2[8][8];
#pragma unroll
    for (int i = 0; i < 8; i++)
#pragma unroll
        for (int j = 0; j < 8; j++) a2[i][j] = 0.f;

    for (int n = 0; n < 32; n++) {
        float4 ka = *(const float4*)(Khs + n * CC + 4 * cg);
        float4 kb = *(const float4*)(Khs + n * CC + 64 + 4 * cg);
        float4 va = *(const float4*)(Vs + n * CC + 4 * dg2);
        float4 vb = *(const float4*)(Vs + n * CC + 64 + 4 * dg2);
        float kc[8] = {ka.x, ka.y, ka.z, ka.w, kb.x, kb.y, kb.z, kb.w};
        float vd[8] = {va.x, va.y, va.z, va.w, vb.x, vb.y, vb.z, vb.w};
#pragma unroll
        for (int i = 0; i < 8; i++)
#pragma unroll
            for (int j = 0; j < 8; j++) a2[i][j] += kc[i] * vd[j];
    }

    float* pp = ws + PP_OFF + (size_t)blk * (CC * CC);
#pragma unroll
    for (int i = 0; i < 8; i++) {
        int c = 4 * cg + (i & 3) + (i >> 2) * 64;
        *(float4*)(pp + c * CC + 4 * dg2) =
            make_float4(a2[i][0], a2[i][1], a2[i][2], a2[i][3]);
        *(float4*)(pp + c * CC + 64 + 4 * dg2) =
            make_float4(a2[i][4], a2[i][5], a2[i][6], a2[i][7]);
    }

    red[nr * 32 + c4] = ksum4;
    __syncthreads();
    if (tid < 32) {
        float4 sm = red[tid];
#pragma unroll
        for (int i = 1; i < 8; i++) {
            float4 t = red[i * 32 + tid];
            sm.x += t.x; sm.y += t.y; sm.z += t.z; sm.w += t.w;
        }
        ((float4*)(ws + KP_OFF + (size_t)blk * CC))[tid] = sm;
    }
}

// ---------------------------------------------------------------------------
// Kernel 2: fused reduce + M-build.
// Grid (64, B): block (x,b) reduces M0 rows {2x, 2x+1} and Ksum entries
// {2x, 2x+1} over the 128 partials of batch b, then computes
//   M[c][e] = sum_d M0[c][d] * W[e][d] + Ksum[c] * b[e]
// ---------------------------------------------------------------------------
__global__ __launch_bounds__(256) void mchain_kernel(const float* __restrict__ W,
                                                     const float* __restrict__ bias,
                                                     float* __restrict__ ws)
{
    __shared__ float4 W4s[CC * 32];    // W natural, float4-swizzled per row
    __shared__ float m0row[2][CC];
    __shared__ float kpart[4];
    __shared__ float ksl[2];
    const int tid = threadIdx.x;
    const int b = blockIdx.y, x = blockIdx.x;
    const int c0 = x * 2;

    for (int idx = tid; idx < CC * 32; idx += 256) {
        int e = idx >> 5, d4 = idx & 31;
        W4s[(e << 5) + (d4 ^ (e & 31))] = ((const float4*)W)[idx];
    }

    // reduce 2 rows of M0 over 128 partials (each thread one element)
    {
        const int r = tid >> 7, d = tid & 127;
        const float* pp = ws + PP_OFF + (size_t)(b * 128) * (CC * CC)
                        + (size_t)(c0 + r) * CC + d;
        float a0 = 0.f, a1 = 0.f, a2 = 0.f, a3 = 0.f;
#pragma unroll 8
        for (int p = 0; p < 128; p += 4) {
            a0 += pp[(size_t)(p + 0) * (CC * CC)];
            a1 += pp[(size_t)(p + 1) * (CC * CC)];
            a2 += pp[(size_t)(p + 2) * (CC * CC)];
            a3 += pp[(size_t)(p + 3) * (CC * CC)];
        }
        m0row[r][d] = (a0 + a1) + (a2 + a3);
    }

    // reduce 2 Ksum entries over 128 partials (2 waves per entry)
    {
        const int rr = tid >> 7, p = tid & 127;
        float v = ws[KP_OFF + (size_t)(b * 128 + p) * CC + c0 + rr];
#pragma unroll
        for (int off = 32; off > 0; off >>= 1) v += __shfl_xor(v, off, 64);
        if ((tid & 63) == 0) kpart[tid >> 6] = v;
    }
    __syncthreads();
    if (tid < 2) {
        float s = kpart[tid * 2] + kpart[tid * 2 + 1];
        ksl[tid] = s;
        ws[KS_OFF + b * CC + c0 + tid] = s;
    }
    __syncthreads();

    // M = M0 @ W^T + Ksum b^T  (thread -> one output element)
    const int r = tid >> 7, e = tid & 127;
    const float4* mr = (const float4*)m0row[r];
    float m = 0.f;
#pragma unroll
    for (int d4 = 0; d4 < 32; d4++) {
        float4 a4 = mr[d4];                              // broadcast
        float4 w4 = W4s[(e << 5) + (d4 ^ (e & 31))];     // conflict-spread
        m += a4.x * w4.x + a4.y * w4.y + a4.z * w4.z + a4.w * w4.w;
    }
    m += ksl[r] * bias[e];
    ws[MM_OFF + (size_t)b * CC * CC + (size_t)(c0 + r) * CC + e] = m;
}

// ---------------------------------------------------------------------------
// Kernel 3: out[b,r,:] = (q_proj[r] @ M) / (q_proj[r].Ksum + 1e-8*|q_proj[r]|)
// ---------------------------------------------------------------------------
__global__ __launch_bounds__(256, 2) void out_kernel(const float* __restrict__ ws,
                                                     float* __restrict__ out)
{
    __shared__ float Ml[CC * CC];

    const int blk = blockIdx.x;     // 0..511
    const int b = blk >> 7;
    const int r0 = (blk & 127) * 32;
    const float* M = ws + MM_OFF + (size_t)b * CC * CC;
    const int tid = threadIdx.x;

    for (int e = tid; e < CC * CC / 4; e += 256)
        ((float4*)Ml)[e] = ((const float4*)M)[e];

    const float4* Ks4 = (const float4*)(ws + KS_OFF + b * CC);
    const int dg = tid & 31, rg = tid >> 5;
    const int row = r0 + rg * 4;
    const float4* Qv = (const float4*)(ws + QP_OFF + ((size_t)b * NN + row) * CC);

    float4 acc[4];
    float s[4];
#pragma unroll
    for (int i = 0; i < 4; i++) {
        acc[i] = make_float4(0.f, 0.f, 0.f, 0.f);
        s[i] = 0.f;
    }

    __syncthreads();

    for (int c = 0; c < CC; c += 4) {
        const int c4 = c >> 2;
        float4 m0 = ((const float4*)Ml)[((c + 0) << 5) + dg];
        float4 m1 = ((const float4*)Ml)[((c + 1) << 5) + dg];
        float4 m2 = ((const float4*)Ml)[((c + 2) << 5) + dg];
        float4 m3 = ((const float4*)Ml)[((c + 3) << 5) + dg];
        float4 ks = Ks4[c4];
#pragma unroll
        for (int i = 0; i < 4; i++) {
            float4 x = Qv[i * 32 + c4];
            acc[i].x += x.x * m0.x + x.y * m1.x + x.z * m2.x + x.w * m3.x;
            acc[i].y += x.x * m0.y + x.y * m1.y + x.z * m2.y + x.w * m3.y;
            acc[i].z += x.x * m0.z + x.y * m1.z + x.z * m2.z + x.w * m3.z;
            acc[i].w += x.x * m0.w + x.y * m1.w + x.z * m2.w + x.w * m3.w;
            s[i] += x.x * ks.x + x.y * ks.y + x.z * ks.z + x.w * ks.w;
        }
    }

    float* op = out + ((size_t)b * NN + row) * CC;
    const float* qn = ws + QN_OFF + (size_t)b * NN + row;
#pragma unroll
    for (int i = 0; i < 4; i++) {
        float inv = 1.0f / (s[i] + 1e-8f * qn[i]);
        float4 o = acc[i];
        o.x *= inv; o.y *= inv; o.z *= inv; o.w *= inv;
        ((float4*)(op + (size_t)i * CC))[dg] = o;
    }
}

// ---------------------------------------------------------------------------
extern "C" void kernel_launch(void* const* d_in, const int* in_sizes, int n_in,
                              void* d_out, int out_size, void* d_ws, size_t ws_size,
                              hipStream_t stream)
{
    const float* q_node = (const float*)d_in[0];
    const float* k_node = (const float*)d_in[1];
    const float* v_node = (const float*)d_in[2];
    const float* W      = (const float*)d_in[3];
    const float* bias   = (const float*)d_in[4];
    float* out = (float*)d_out;
    float* ws  = (float*)d_ws;

    projpb_kernel<<<512, 256, 0, stream>>>(q_node, k_node, v_node, W, bias, ws);
    mchain_kernel<<<dim3(64, BB), 256, 0, stream>>>(W, bias, ws);
    out_kernel<<<512, 256, 0, stream>>>(ws, out);
}

// Round 2
// 138.646 us; speedup vs baseline: 1.0975x; 1.0405x over previous
//
#include <hip/hip_runtime.h>

#define BB 4
#define NN 4096
#define CC 128
#define NROWS (BB * NN)   // 16384 rows per tensor

// workspace layout (float offsets)
#define QN_OFF  0                              // |q_proj| per row (16384)
#define QP_OFF  (QN_OFF + NROWS)               // projected q, 16384 x 128
#define MM_OFF  (QP_OFF + NROWS * CC)          // B x 128 x 128  M = M0 W^T + Ksum b^T
#define KS_OFF  (MM_OFF + BB * CC * CC)        // B x 128  Ksum (sum of khat rows)
#define PP_OFF  (KS_OFF + BB * CC)             // 512 x 16384 partial M0s
#define KP_OFF  (PP_OFF + 512 * CC * CC)       // 512 x 128 partial ksums

// ---------------------------------------------------------------------------
// Kernel 1: symmetric fused projection + partial-M build, 512-thread blocks.
// 512 blocks x 512 threads; LDS 72KB -> 2 blocks/CU -> 16 waves/CU (vs 8
// with 256-thread blocks). Each block: project 32 q rows (store q_proj +
// norms) and 32 k rows (normalize into LDS), then rank-32 partial M0 + ksum.
// ---------------------------------------------------------------------------
__global__ __launch_bounds__(512, 4) void projpb_kernel(
    const float* __restrict__ q_node, const float* __restrict__ k_node,
    const float* __restrict__ v_node, const float* __restrict__ W,
    const float* __restrict__ bias, float* __restrict__ ws)
{
    __shared__ float S[CC * CC];    // phase 1: swizzled W^T; phase 2: khat|v tiles
    __shared__ float4 red[512];
    const int tid = threadIdx.x;

    for (int e = tid; e < CC * CC; e += 512) {
        int d = e >> 7, c = e & 127;
        S[(c << 7) + ((((d >> 2) ^ (c & 31)) << 2) | (d & 3))] = W[e];
    }

    const int blk  = blockIdx.x;        // 0..511
    const int base = blk * 32;          // row base (same rows in q and k tensors)
    const int dg = tid & 31;            // output-dim group (4 dims)
    const int rg = tid >> 5;            // 0..15, 2 rows each

    float4 bias4 = ((const float4*)bias)[dg];
    float4 acc[4];                      // q0,q1,k0,k1
#pragma unroll
    for (int i = 0; i < 4; i++) acc[i] = bias4;

    __syncthreads();

    const float4* Qv = (const float4*)(q_node + (size_t)(base + rg * 2) * CC);
    const float4* Kv = (const float4*)(k_node + (size_t)(base + rg * 2) * CC);

    for (int c = 0; c < CC; c += 4) {
        const int c4 = c >> 2;
        float4 w0 = ((const float4*)S)[((c + 0) << 5) + (dg ^ ((c + 0) & 31))];
        float4 w1 = ((const float4*)S)[((c + 1) << 5) + (dg ^ ((c + 1) & 31))];
        float4 w2 = ((const float4*)S)[((c + 2) << 5) + (dg ^ ((c + 2) & 31))];
        float4 w3 = ((const float4*)S)[((c + 3) << 5) + (dg ^ ((c + 3) & 31))];
#pragma unroll
        for (int i = 0; i < 2; i++) {
            float4 x = Qv[i * 32 + c4];
            acc[i].x += x.x * w0.x + x.y * w1.x + x.z * w2.x + x.w * w3.x;
            acc[i].y += x.x * w0.y + x.y * w1.y + x.z * w2.y + x.w * w3.y;
            acc[i].z += x.x * w0.z + x.y * w1.z + x.z * w2.z + x.w * w3.z;
            acc[i].w += x.x * w0.w + x.y * w1.w + x.z * w2.w + x.w * w3.w;
            float4 y = Kv[i * 32 + c4];
            acc[2 + i].x += y.x * w0.x + y.y * w1.x + y.z * w2.x + y.w * w3.x;
            acc[2 + i].y += y.x * w0.y + y.y * w1.y + y.z * w2.y + y.w * w3.y;
            acc[2 + i].z += y.x * w0.z + y.y * w1.z + y.z * w2.z + y.w * w3.z;
            acc[2 + i].w += y.x * w0.w + y.y * w1.w + y.z * w2.w + y.w * w3.w;
        }
    }

    // q rows: store projected row + norm
#pragma unroll
    for (int i = 0; i < 2; i++) {
        const int rq = base + rg * 2 + i;
        float ss = acc[i].x * acc[i].x + acc[i].y * acc[i].y
                 + acc[i].z * acc[i].z + acc[i].w * acc[i].w;
#pragma unroll
        for (int off = 16; off > 0; off >>= 1) ss += __shfl_xor(ss, off, 32);
        ((float4*)(ws + QP_OFF + (size_t)rq * CC))[dg] = acc[i];
        if (dg == 0) ws[QN_OFF + rq] = sqrtf(ss);
    }

    __syncthreads();   // everyone done reading W before LDS reuse

    float* Khs = S;            // 32 x 128 (16 KB)
    float* Vs  = S + 4096;     // 32 x 128 (16 KB)

    // k rows: normalize into LDS
#pragma unroll
    for (int i = 0; i < 2; i++) {
        float ss = acc[2 + i].x * acc[2 + i].x + acc[2 + i].y * acc[2 + i].y
                 + acc[2 + i].z * acc[2 + i].z + acc[2 + i].w * acc[2 + i].w;
#pragma unroll
        for (int off = 16; off > 0; off >>= 1) ss += __shfl_xor(ss, off, 32);
        float inv = 1.0f / sqrtf(ss);
        float4 o = acc[2 + i];
        o.x *= inv; o.y *= inv; o.z *= inv; o.w *= inv;
        ((float4*)(Khs + (rg * 2 + i) * CC))[dg] = o;
    }

    // stage v rows 32x128 (each thread 2 float4)
    const int c4v = tid & 31, nrv = tid >> 5;   // nrv 0..15
    const float* Vp = v_node + (size_t)base * CC;
#pragma unroll
    for (int i = 0; i < 2; i++) {
        int n = nrv + i * 16;
        ((float4*)(Vs + n * CC))[c4v] = ((const float4*)(Vp + (size_t)n * CC))[c4v];
    }
    __syncthreads();

    // partial ksum (column sums of khat)
    float4 ksum4 = make_float4(0.f, 0.f, 0.f, 0.f);
#pragma unroll
    for (int i = 0; i < 2; i++) {
        int n = nrv + i * 16;
        float4 kv = ((const float4*)(Khs + n * CC))[c4v];
        ksum4.x += kv.x; ksum4.y += kv.y; ksum4.z += kv.z; ksum4.w += kv.w;
    }

    // rank-32 outer product: thread -> 4x8 tile of the 128x128 partial
    const int dg2 = tid & 15, cg = tid >> 4;    // cg 0..31
    float a2[4][8];
#pragma unroll
    for (int i = 0; i < 4; i++)
#pragma unroll
        for (int j = 0; j < 8; j++) a2[i][j] = 0.f;

    for (int n = 0; n < 32; n++) {
        float4 ka = *(const float4*)(Khs + n * CC + 4 * cg);
        float4 va = *(const float4*)(Vs + n * CC + 4 * dg2);
        float4 vb = *(const float4*)(Vs + n * CC + 64 + 4 * dg2);
        float kc[4] = {ka.x, ka.y, ka.z, ka.w};
        float vd[8] = {va.x, va.y, va.z, va.w, vb.x, vb.y, vb.z, vb.w};
#pragma unroll
        for (int i = 0; i < 4; i++)
#pragma unroll
            for (int j = 0; j < 8; j++) a2[i][j] += kc[i] * vd[j];
    }

    float* pp = ws + PP_OFF + (size_t)blk * (CC * CC);
#pragma unroll
    for (int i = 0; i < 4; i++) {
        int c = 4 * cg + i;
        *(float4*)(pp + c * CC + 4 * dg2) =
            make_float4(a2[i][0], a2[i][1], a2[i][2], a2[i][3]);
        *(float4*)(pp + c * CC + 64 + 4 * dg2) =
            make_float4(a2[i][4], a2[i][5], a2[i][6], a2[i][7]);
    }

    red[nrv * 32 + c4v] = ksum4;
    __syncthreads();
    if (tid < 32) {
        float4 sm = red[tid];
#pragma unroll
        for (int i = 1; i < 16; i++) {
            float4 t = red[i * 32 + tid];
            sm.x += t.x; sm.y += t.y; sm.z += t.z; sm.w += t.w;
        }
        ((float4*)(ws + KP_OFF + (size_t)blk * CC))[tid] = sm;
    }
}

// ---------------------------------------------------------------------------
// Kernel 2: fused reduce + M-build.
// Grid (64, B): block (x,b) reduces M0 rows {2x, 2x+1} and Ksum entries
// {2x, 2x+1} over the 128 partials of batch b, then computes
//   M[c][e] = sum_d M0[c][d] * W[e][d] + Ksum[c] * b[e]
// ---------------------------------------------------------------------------
__global__ __launch_bounds__(256) void mchain_kernel(const float* __restrict__ W,
                                                     const float* __restrict__ bias,
                                                     float* __restrict__ ws)
{
    __shared__ float4 W4s[CC * 32];    // W natural, float4-swizzled per row
    __shared__ float m0row[2][CC];
    __shared__ float kpart[4];
    __shared__ float ksl[2];
    const int tid = threadIdx.x;
    const int b = blockIdx.y, x = blockIdx.x;
    const int c0 = x * 2;

    for (int idx = tid; idx < CC * 32; idx += 256) {
        int e = idx >> 5, d4 = idx & 31;
        W4s[(e << 5) + (d4 ^ (e & 31))] = ((const float4*)W)[idx];
    }

    // reduce 2 rows of M0 over 128 partials (each thread one element)
    {
        const int r = tid >> 7, d = tid & 127;
        const float* pp = ws + PP_OFF + (size_t)(b * 128) * (CC * CC)
                        + (size_t)(c0 + r) * CC + d;
        float a0 = 0.f, a1 = 0.f, a2 = 0.f, a3 = 0.f;
#pragma unroll 8
        for (int p = 0; p < 128; p += 4) {
            a0 += pp[(size_t)(p + 0) * (CC * CC)];
            a1 += pp[(size_t)(p + 1) * (CC * CC)];
            a2 += pp[(size_t)(p + 2) * (CC * CC)];
            a3 += pp[(size_t)(p + 3) * (CC * CC)];
        }
        m0row[r][d] = (a0 + a1) + (a2 + a3);
    }

    // reduce 2 Ksum entries over 128 partials (2 waves per entry)
    {
        const int rr = tid >> 7, p = tid & 127;
        float v = ws[KP_OFF + (size_t)(b * 128 + p) * CC + c0 + rr];
#pragma unroll
        for (int off = 32; off > 0; off >>= 1) v += __shfl_xor(v, off, 64);
        if ((tid & 63) == 0) kpart[tid >> 6] = v;
    }
    __syncthreads();
    if (tid < 2) {
        float s = kpart[tid * 2] + kpart[tid * 2 + 1];
        ksl[tid] = s;
        ws[KS_OFF + b * CC + c0 + tid] = s;
    }
    __syncthreads();

    // M = M0 @ W^T + Ksum b^T  (thread -> one output element)
    const int r = tid >> 7, e = tid & 127;
    const float4* mr = (const float4*)m0row[r];
    float m = 0.f;
#pragma unroll
    for (int d4 = 0; d4 < 32; d4++) {
        float4 a4 = mr[d4];                              // broadcast
        float4 w4 = W4s[(e << 5) + (d4 ^ (e & 31))];     // conflict-spread
        m += a4.x * w4.x + a4.y * w4.y + a4.z * w4.z + a4.w * w4.w;
    }
    m += ksl[r] * bias[e];
    ws[MM_OFF + (size_t)b * CC * CC + (size_t)(c0 + r) * CC + e] = m;
}

// ---------------------------------------------------------------------------
// Kernel 3: out[b,r,:] = (q_proj[r] @ M) / (q_proj[r].Ksum + 1e-8*|q_proj[r]|)
// 512-thread blocks, 32 rows each -> 2 blocks/CU, 16 waves/CU.
// ---------------------------------------------------------------------------
__global__ __launch_bounds__(512, 4) void out_kernel(const float* __restrict__ ws,
                                                     float* __restrict__ out)
{
    __shared__ float Ml[CC * CC];

    const int blk = blockIdx.x;     // 0..511
    const int b = blk >> 7;
    const int r0 = (blk & 127) * 32;
    const float* M = ws + MM_OFF + (size_t)b * CC * CC;
    const int tid = threadIdx.x;

    for (int e = tid; e < CC * CC / 4; e += 512)
        ((float4*)Ml)[e] = ((const float4*)M)[e];

    const float4* Ks4 = (const float4*)(ws + KS_OFF + b * CC);
    const int dg = tid & 31, rg = tid >> 5;   // rg 0..15, 2 rows each
    const int row = r0 + rg * 2;
    const float4* Qv = (const float4*)(ws + QP_OFF + ((size_t)b * NN + row) * CC);

    float4 acc[2];
    float s[2];
#pragma unroll
    for (int i = 0; i < 2; i++) {
        acc[i] = make_float4(0.f, 0.f, 0.f, 0.f);
        s[i] = 0.f;
    }

    __syncthreads();

    for (int c = 0; c < CC; c += 4) {
        const int c4 = c >> 2;
        float4 m0 = ((const float4*)Ml)[((c + 0) << 5) + dg];
        float4 m1 = ((const float4*)Ml)[((c + 1) << 5) + dg];
        float4 m2 = ((const float4*)Ml)[((c + 2) << 5) + dg];
        float4 m3 = ((const float4*)Ml)[((c + 3) << 5) + dg];
        float4 ks = Ks4[c4];
#pragma unroll
        for (int i = 0; i < 2; i++) {
            float4 x = Qv[i * 32 + c4];
            acc[i].x += x.x * m0.x + x.y * m1.x + x.z * m2.x + x.w * m3.x;
            acc[i].y += x.x * m0.y + x.y * m1.y + x.z * m2.y + x.w * m3.y;
            acc[i].z += x.x * m0.z + x.y * m1.z + x.z * m2.z + x.w * m3.z;
            acc[i].w += x.x * m0.w + x.y * m1.w + x.z * m2.w + x.w * m3.w;
            s[i] += x.x * ks.x + x.y * ks.y + x.z * ks.z + x.w * ks.w;
        }
    }

    float* op = out + ((size_t)b * NN + row) * CC;
    const float* qn = ws + QN_OFF + (size_t)b * NN + row;
#pragma unroll
    for (int i = 0; i < 2; i++) {
        float inv = 1.0f / (s[i] + 1e-8f * qn[i]);
        float4 o = acc[i];
        o.x *= inv; o.y *= inv; o.z *= inv; o.w *= inv;
        ((float4*)(op + (size_t)i * CC))[dg] = o;
    }
}

// ---------------------------------------------------------------------------
extern "C" void kernel_launch(void* const* d_in, const int* in_sizes, int n_in,
                              void* d_out, int out_size, void* d_ws, size_t ws_size,
                              hipStream_t stream)
{
    const float* q_node = (const float*)d_in[0];
    const float* k_node = (const float*)d_in[1];
    const float* v_node = (const float*)d_in[2];
    const float* W      = (const float*)d_in[3];
    const float* bias   = (const float*)d_in[4];
    float* out = (float*)d_out;
    float* ws  = (float*)d_ws;

    projpb_kernel<<<512, 512, 0, stream>>>(q_node, k_node, v_node, W, bias, ws);
    mchain_kernel<<<dim3(64, BB), 256, 0, stream>>>(W, bias, ws);
    out_kernel<<<512, 512, 0, stream>>>(ws, out);
}

// Round 3
// 133.629 us; speedup vs baseline: 1.1387x; 1.0375x over previous
//
#include <hip/hip_runtime.h>

#define BB 4
#define NN 4096
#define CC 128
#define NROWS (BB * NN)   // 16384 rows per tensor

// workspace layout (float offsets)
#define QN_OFF  0                              // |q_proj| per row (16384)
#define QP_OFF  (QN_OFF + NROWS)               // projected q, 16384 x 128
#define MM_OFF  (QP_OFF + NROWS * CC)          // B x 128 x 128  M = M0 W^T + Ksum b^T
#define KS_OFF  (MM_OFF + BB * CC * CC)        // B x 128  Ksum (sum of khat rows)
#define PP_OFF  (KS_OFF + BB * CC)             // 512 x 16384 partial M0s
#define KP_OFF  (PP_OFF + 512 * CC * CC)       // 512 x 128 partial ksums

__device__ __forceinline__ void fma4(float4& a, const float4 x,
    const float4 w0, const float4 w1, const float4 w2, const float4 w3)
{
    a.x += x.x * w0.x + x.y * w1.x + x.z * w2.x + x.w * w3.x;
    a.y += x.x * w0.y + x.y * w1.y + x.z * w2.y + x.w * w3.y;
    a.z += x.x * w0.z + x.y * w1.z + x.z * w2.z + x.w * w3.z;
    a.w += x.x * w0.w + x.y * w1.w + x.z * w2.w + x.w * w3.w;
}

// ---------------------------------------------------------------------------
// Kernel 1: symmetric fused projection + partial-M build, 512-thread blocks,
// with manual 2-stage software pipelining (register double-buffer A/B) so
// LDS reads / global loads for step t+1 are in flight during step t's FMAs.
// ---------------------------------------------------------------------------
__global__ __launch_bounds__(512, 4) void projpb_kernel(
    const float* __restrict__ q_node, const float* __restrict__ k_node,
    const float* __restrict__ v_node, const float* __restrict__ W,
    const float* __restrict__ bias, float* __restrict__ ws)
{
    __shared__ float S[CC * CC];    // phase 1: swizzled W^T; phase 2: khat|v tiles
    __shared__ float4 red[512];
    const int tid = threadIdx.x;

    for (int e = tid; e < CC * CC; e += 512) {
        int d = e >> 7, c = e & 127;
        S[(c << 7) + ((((d >> 2) ^ (c & 31)) << 2) | (d & 3))] = W[e];
    }

    const int blk  = blockIdx.x;        // 0..511
    const int base = blk * 32;          // row base (same rows in q and k tensors)
    const int dg = tid & 31;            // output-dim group (4 dims)
    const int rg = tid >> 5;            // 0..15, 2 rows each

    float4 bias4 = ((const float4*)bias)[dg];
    float4 acc[4];                      // q0,q1,k0,k1
#pragma unroll
    for (int i = 0; i < 4; i++) acc[i] = bias4;

    __syncthreads();

    const float4* Qv = (const float4*)(q_node + (size_t)(base + rg * 2) * CC);
    const float4* Kv = (const float4*)(k_node + (size_t)(base + rg * 2) * CC);
    const float4* Sv = (const float4*)S;

#define LW(s0, s1, s2, s3, c)                              \
    s0 = Sv[(((c) + 0) << 5) + (dg ^ (((c) + 0) & 31))];   \
    s1 = Sv[(((c) + 1) << 5) + (dg ^ (((c) + 1) & 31))];   \
    s2 = Sv[(((c) + 2) << 5) + (dg ^ (((c) + 2) & 31))];   \
    s3 = Sv[(((c) + 3) << 5) + (dg ^ (((c) + 3) & 31))];
#define LX(q0, q1, k0, k1, c)                              \
    { const int c4_ = (c) >> 2;                            \
      q0 = Qv[c4_]; q1 = Qv[32 + c4_];                     \
      k0 = Kv[c4_]; k1 = Kv[32 + c4_]; }
#define FM(w0, w1, w2, w3, q0, q1, k0, k1)                 \
    fma4(acc[0], q0, w0, w1, w2, w3);                      \
    fma4(acc[1], q1, w0, w1, w2, w3);                      \
    fma4(acc[2], k0, w0, w1, w2, w3);                      \
    fma4(acc[3], k1, w0, w1, w2, w3);

    float4 wA0, wA1, wA2, wA3, wB0, wB1, wB2, wB3;
    float4 qA0, qA1, kA0, kA1, qB0, qB1, kB0, kB1;

    LW(wA0, wA1, wA2, wA3, 0)
    LX(qA0, qA1, kA0, kA1, 0)
    for (int c = 0; c <= CC - 16; c += 8) {
        LW(wB0, wB1, wB2, wB3, c + 4)
        LX(qB0, qB1, kB0, kB1, c + 4)
        FM(wA0, wA1, wA2, wA3, qA0, qA1, kA0, kA1)
        LW(wA0, wA1, wA2, wA3, c + 8)
        LX(qA0, qA1, kA0, kA1, c + 8)
        FM(wB0, wB1, wB2, wB3, qB0, qB1, kB0, kB1)
    }
    LW(wB0, wB1, wB2, wB3, CC - 4)
    LX(qB0, qB1, kB0, kB1, CC - 4)
    FM(wA0, wA1, wA2, wA3, qA0, qA1, kA0, kA1)
    FM(wB0, wB1, wB2, wB3, qB0, qB1, kB0, kB1)

#undef LW
#undef LX
#undef FM

    // q rows: store projected row + norm
#pragma unroll
    for (int i = 0; i < 2; i++) {
        const int rq = base + rg * 2 + i;
        float ss = acc[i].x * acc[i].x + acc[i].y * acc[i].y
                 + acc[i].z * acc[i].z + acc[i].w * acc[i].w;
#pragma unroll
        for (int off = 16; off > 0; off >>= 1) ss += __shfl_xor(ss, off, 32);
        ((float4*)(ws + QP_OFF + (size_t)rq * CC))[dg] = acc[i];
        if (dg == 0) ws[QN_OFF + rq] = sqrtf(ss);
    }

    __syncthreads();   // everyone done reading W before LDS reuse

    float* Khs = S;            // 32 x 128 (16 KB)
    float* Vs  = S + 4096;     // 32 x 128 (16 KB)

    // k rows: normalize into LDS
#pragma unroll
    for (int i = 0; i < 2; i++) {
        float ss = acc[2 + i].x * acc[2 + i].x + acc[2 + i].y * acc[2 + i].y
                 + acc[2 + i].z * acc[2 + i].z + acc[2 + i].w * acc[2 + i].w;
#pragma unroll
        for (int off = 16; off > 0; off >>= 1) ss += __shfl_xor(ss, off, 32);
        float inv = 1.0f / sqrtf(ss);
        float4 o = acc[2 + i];
        o.x *= inv; o.y *= inv; o.z *= inv; o.w *= inv;
        ((float4*)(Khs + (rg * 2 + i) * CC))[dg] = o;
    }

    // stage v rows 32x128 (each thread 2 float4)
    const int c4v = tid & 31, nrv = tid >> 5;   // nrv 0..15
    const float* Vp = v_node + (size_t)base * CC;
#pragma unroll
    for (int i = 0; i < 2; i++) {
        int n = nrv + i * 16;
        ((float4*)(Vs + n * CC))[c4v] = ((const float4*)(Vp + (size_t)n * CC))[c4v];
    }
    __syncthreads();

    // partial ksum (column sums of khat)
    float4 ksum4 = make_float4(0.f, 0.f, 0.f, 0.f);
#pragma unroll
    for (int i = 0; i < 2; i++) {
        int n = nrv + i * 16;
        float4 kv = ((const float4*)(Khs + n * CC))[c4v];
        ksum4.x += kv.x; ksum4.y += kv.y; ksum4.z += kv.z; ksum4.w += kv.w;
    }

    // rank-32 outer product, software-pipelined over n
    const int dg2 = tid & 15, cg = tid >> 4;    // cg 0..31
    float a2[4][8];
#pragma unroll
    for (int i = 0; i < 4; i++)
#pragma unroll
        for (int j = 0; j < 8; j++) a2[i][j] = 0.f;

#define P2L(ka, va, vb, n)                                  \
    ka = *(const float4*)(Khs + (n) * CC + 4 * cg);         \
    va = *(const float4*)(Vs + (n) * CC + 4 * dg2);         \
    vb = *(const float4*)(Vs + (n) * CC + 64 + 4 * dg2);
#define P2F(ka, va, vb)                                     \
    {  float kc[4] = {ka.x, ka.y, ka.z, ka.w};              \
       float vd[8] = {va.x, va.y, va.z, va.w,               \
                      vb.x, vb.y, vb.z, vb.w};              \
       _Pragma("unroll")                                    \
       for (int i = 0; i < 4; i++)                          \
           { _Pragma("unroll")                              \
             for (int j = 0; j < 8; j++)                    \
                 a2[i][j] += kc[i] * vd[j]; } }

    {
        float4 kaA, vaA, vbA, kaB, vaB, vbB;
        P2L(kaA, vaA, vbA, 0)
        for (int n = 0; n <= 28; n += 2) {
            P2L(kaB, vaB, vbB, n + 1)
            P2F(kaA, vaA, vbA)
            P2L(kaA, vaA, vbA, n + 2)
            P2F(kaB, vaB, vbB)
        }
        P2L(kaB, vaB, vbB, 31)
        P2F(kaA, vaA, vbA)
        P2F(kaB, vaB, vbB)
    }
#undef P2L
#undef P2F

    float* pp = ws + PP_OFF + (size_t)blk * (CC * CC);
#pragma unroll
    for (int i = 0; i < 4; i++) {
        int c = 4 * cg + i;
        *(float4*)(pp + c * CC + 4 * dg2) =
            make_float4(a2[i][0], a2[i][1], a2[i][2], a2[i][3]);
        *(float4*)(pp + c * CC + 64 + 4 * dg2) =
            make_float4(a2[i][4], a2[i][5], a2[i][6], a2[i][7]);
    }

    red[nrv * 32 + c4v] = ksum4;
    __syncthreads();
    if (tid < 32) {
        float4 sm = red[tid];
#pragma unroll
        for (int i = 1; i < 16; i++) {
            float4 t = red[i * 32 + tid];
            sm.x += t.x; sm.y += t.y; sm.z += t.z; sm.w += t.w;
        }
        ((float4*)(ws + KP_OFF + (size_t)blk * CC))[tid] = sm;
    }
}

// ---------------------------------------------------------------------------
// Kernel 2: fused reduce + M-build (unchanged; BW-bound streaming).
// ---------------------------------------------------------------------------
__global__ __launch_bounds__(256) void mchain_kernel(const float* __restrict__ W,
                                                     const float* __restrict__ bias,
                                                     float* __restrict__ ws)
{
    __shared__ float4 W4s[CC * 32];    // W natural, float4-swizzled per row
    __shared__ float m0row[2][CC];
    __shared__ float kpart[4];
    __shared__ float ksl[2];
    const int tid = threadIdx.x;
    const int b = blockIdx.y, x = blockIdx.x;
    const int c0 = x * 2;

    for (int idx = tid; idx < CC * 32; idx += 256) {
        int e = idx >> 5, d4 = idx & 31;
        W4s[(e << 5) + (d4 ^ (e & 31))] = ((const float4*)W)[idx];
    }

    // reduce 2 rows of M0 over 128 partials (each thread one element)
    {
        const int r = tid >> 7, d = tid & 127;
        const float* pp = ws + PP_OFF + (size_t)(b * 128) * (CC * CC)
                        + (size_t)(c0 + r) * CC + d;
        float a0 = 0.f, a1 = 0.f, a2 = 0.f, a3 = 0.f;
#pragma unroll 8
        for (int p = 0; p < 128; p += 4) {
            a0 += pp[(size_t)(p + 0) * (CC * CC)];
            a1 += pp[(size_t)(p + 1) * (CC * CC)];
            a2 += pp[(size_t)(p + 2) * (CC * CC)];
            a3 += pp[(size_t)(p + 3) * (CC * CC)];
        }
        m0row[r][d] = (a0 + a1) + (a2 + a3);
    }

    // reduce 2 Ksum entries over 128 partials (2 waves per entry)
    {
        const int rr = tid >> 7, p = tid & 127;
        float v = ws[KP_OFF + (size_t)(b * 128 + p) * CC + c0 + rr];
#pragma unroll
        for (int off = 32; off > 0; off >>= 1) v += __shfl_xor(v, off, 64);
        if ((tid & 63) == 0) kpart[tid >> 6] = v;
    }
    __syncthreads();
    if (tid < 2) {
        float s = kpart[tid * 2] + kpart[tid * 2 + 1];
        ksl[tid] = s;
        ws[KS_OFF + b * CC + c0 + tid] = s;
    }
    __syncthreads();

    // M = M0 @ W^T + Ksum b^T  (thread -> one output element)
    const int r = tid >> 7, e = tid & 127;
    const float4* mr = (const float4*)m0row[r];
    float m = 0.f;
#pragma unroll
    for (int d4 = 0; d4 < 32; d4++) {
        float4 a4 = mr[d4];                              // broadcast
        float4 w4 = W4s[(e << 5) + (d4 ^ (e & 31))];     // conflict-spread
        m += a4.x * w4.x + a4.y * w4.y + a4.z * w4.z + a4.w * w4.w;
    }
    m += ksl[r] * bias[e];
    ws[MM_OFF + (size_t)b * CC * CC + (size_t)(c0 + r) * CC + e] = m;
}

// ---------------------------------------------------------------------------
// Kernel 3: out[b,r,:] = (q_proj[r] @ M) / (q_proj[r].Ksum + 1e-8*|q_proj[r]|)
// 512-thread blocks, software-pipelined c-loop.
// ---------------------------------------------------------------------------
__global__ __launch_bounds__(512, 4) void out_kernel(const float* __restrict__ ws,
                                                     float* __restrict__ out)
{
    __shared__ float Ml[CC * CC];

    const int blk = blockIdx.x;     // 0..511
    const int b = blk >> 7;
    const int r0 = (blk & 127) * 32;
    const float* M = ws + MM_OFF + (size_t)b * CC * CC;
    const int tid = threadIdx.x;

    for (int e = tid; e < CC * CC / 4; e += 512)
        ((float4*)Ml)[e] = ((const float4*)M)[e];

    const float4* Ks4 = (const float4*)(ws + KS_OFF + b * CC);
    const int dg = tid & 31, rg = tid >> 5;   // rg 0..15, 2 rows each
    const int row = r0 + rg * 2;
    const float4* Qv = (const float4*)(ws + QP_OFF + ((size_t)b * NN + row) * CC);
    const float4* Mv = (const float4*)Ml;

    float4 acc[2];
    float s[2];
#pragma unroll
    for (int i = 0; i < 2; i++) {
        acc[i] = make_float4(0.f, 0.f, 0.f, 0.f);
        s[i] = 0.f;
    }

    __syncthreads();

#define OLW(m0, m1, m2, m3, ks, c)               \
    m0 = Mv[(((c) + 0) << 5) + dg];              \
    m1 = Mv[(((c) + 1) << 5) + dg];              \
    m2 = Mv[(((c) + 2) << 5) + dg];              \
    m3 = Mv[(((c) + 3) << 5) + dg];              \
    ks = Ks4[(c) >> 2];
#define OLX(x0, x1, c)                           \
    { const int c4_ = (c) >> 2;                  \
      x0 = Qv[c4_]; x1 = Qv[32 + c4_]; }
#define OFM(m0, m1, m2, m3, ks, x0, x1)                              \
    fma4(acc[0], x0, m0, m1, m2, m3);                                \
    s[0] += x0.x * ks.x + x0.y * ks.y + x0.z * ks.z + x0.w * ks.w;   \
    fma4(acc[1], x1, m0, m1, m2, m3);                                \
    s[1] += x1.x * ks.x + x1.y * ks.y + x1.z * ks.z + x1.w * ks.w;

    {
        float4 mA0, mA1, mA2, mA3, mB0, mB1, mB2, mB3;
        float4 ksA, ksB, xA0, xA1, xB0, xB1;
        OLW(mA0, mA1, mA2, mA3, ksA, 0)
        OLX(xA0, xA1, 0)
        for (int c = 0; c <= CC - 16; c += 8) {
            OLW(mB0, mB1, mB2, mB3, ksB, c + 4)
            OLX(xB0, xB1, c + 4)
            OFM(mA0, mA1, mA2, mA3, ksA, xA0, xA1)
            OLW(mA0, mA1, mA2, mA3, ksA, c + 8)
            OLX(xA0, xA1, c + 8)
            OFM(mB0, mB1, mB2, mB3, ksB, xB0, xB1)
        }
        OLW(mB0, mB1, mB2, mB3, ksB, CC - 4)
        OLX(xB0, xB1, CC - 4)
        OFM(mA0, mA1, mA2, mA3, ksA, xA0, xA1)
        OFM(mB0, mB1, mB2, mB3, ksB, xB0, xB1)
    }
#undef OLW
#undef OLX
#undef OFM

    float* op = out + ((size_t)b * NN + row) * CC;
    const float* qn = ws + QN_OFF + (size_t)b * NN + row;
#pragma unroll
    for (int i = 0; i < 2; i++) {
        float inv = 1.0f / (s[i] + 1e-8f * qn[i]);
        float4 o = acc[i];
        o.x *= inv; o.y *= inv; o.z *= inv; o.w *= inv;
        ((float4*)(op + (size_t)i * CC))[dg] = o;
    }
}

// ---------------------------------------------------------------------------
extern "C" void kernel_launch(void* const* d_in, const int* in_sizes, int n_in,
                              void* d_out, int out_size, void* d_ws, size_t ws_size,
                              hipStream_t stream)
{
    const float* q_node = (const float*)d_in[0];
    const float* k_node = (const float*)d_in[1];
    const float* v_node = (const float*)d_in[2];
    const float* W      = (const float*)d_in[3];
    const float* bias   = (const float*)d_in[4];
    float* out = (float*)d_out;
    float* ws  = (float*)d_ws;

    projpb_kernel<<<512, 512, 0, stream>>>(q_node, k_node, v_node, W, bias, ws);
    mchain_kernel<<<dim3(64, BB), 256, 0, stream>>>(W, bias, ws);
    out_kernel<<<512, 512, 0, stream>>>(ws, out);
}

// Round 5
// 130.599 us; speedup vs baseline: 1.1651x; 1.0232x over previous
//
#include <hip/hip_runtime.h>

#define BB 4
#define NN 4096
#define CC 128
#define NROWS (BB * NN)   // 16384 rows per tensor

// workspace layout (float offsets)
#define QN_OFF  0                              // |q_proj| per row (16384)
#define QP_OFF  (QN_OFF + NROWS)               // projected q, 16384 x 128
#define MM_OFF  (QP_OFF + NROWS * CC)          // B x 128 x 128  M = M0 W^T + Ksum b^T
#define KS_OFF  (MM_OFF + BB * CC * CC)        // B x 128  Ksum (sum of khat rows)
#define PP_OFF  (KS_OFF + BB * CC)             // 256 x 16384 partial M0s
#define KP_OFF  (PP_OFF + 256 * CC * CC)       // 256 x 128 partial ksums

__device__ __forceinline__ void fma4(float4& a, const float4 x,
    const float4 w0, const float4 w1, const float4 w2, const float4 w3)
{
    a.x += x.x * w0.x + x.y * w1.x + x.z * w2.x + x.w * w3.x;
    a.y += x.x * w0.y + x.y * w1.y + x.z * w2.y + x.w * w3.y;
    a.z += x.x * w0.z + x.y * w1.z + x.z * w2.z + x.w * w3.z;
    a.w += x.x * w0.w + x.y * w1.w + x.z * w2.w + x.w * w3.w;
}

__device__ __forceinline__ float dot4(const float4 x, const float4 k)
{
    return x.x * k.x + x.y * k.y + x.z * k.z + x.w * k.w;
}

// ---------------------------------------------------------------------------
// Kernel 1: fused projection + partial-M build.
// 256 blocks x 512 threads, 64 rows (q and k) per block, 8 row-accs per
// thread so each LDS W-read feeds 128 FMAs (2x the previous ratio ->
// LDS pipe no longer the floor). 2-stage register pipeline retained.
// ---------------------------------------------------------------------------
__global__ __launch_bounds__(512, 2) void projpb_kernel(
    const float* __restrict__ q_node, const float* __restrict__ k_node,
    const float* __restrict__ v_node, const float* __restrict__ W,
    const float* __restrict__ bias, float* __restrict__ ws)
{
    __shared__ float S[CC * CC];    // phase 1: swizzled W^T; phase 2: khat|v tiles
    __shared__ float4 red[512];
    const int tid = threadIdx.x;

    for (int e = tid; e < CC * CC; e += 512) {
        int d = e >> 7, c = e & 127;
        S[(c << 7) + ((((d >> 2) ^ (c & 31)) << 2) | (d & 3))] = W[e];
    }

    const int blk  = blockIdx.x;        // 0..255
    const int base = blk * 64;          // row base (same rows in q and k tensors)
    const int dg = tid & 31;            // output-dim group (4 dims)
    const int rg = tid >> 5;            // 0..15, 4 rows each

    float4 bias4 = ((const float4*)bias)[dg];
    float4 acc[8];                      // q0..q3, k0..k3
#pragma unroll
    for (int i = 0; i < 8; i++) acc[i] = bias4;

    __syncthreads();

    const float4* Qv = (const float4*)(q_node + (size_t)(base + rg * 4) * CC);
    const float4* Kv = (const float4*)(k_node + (size_t)(base + rg * 4) * CC);
    const float4* Sv = (const float4*)S;

#define LW(s0, s1, s2, s3, c)                              \
    s0 = Sv[(((c) + 0) << 5) + (dg ^ (((c) + 0) & 31))];   \
    s1 = Sv[(((c) + 1) << 5) + (dg ^ (((c) + 1) & 31))];   \
    s2 = Sv[(((c) + 2) << 5) + (dg ^ (((c) + 2) & 31))];   \
    s3 = Sv[(((c) + 3) << 5) + (dg ^ (((c) + 3) & 31))];
#define LX(xq, xk, c)                                      \
    { const int c4_ = (c) >> 2;                            \
      xq[0] = Qv[c4_];      xq[1] = Qv[32 + c4_];          \
      xq[2] = Qv[64 + c4_]; xq[3] = Qv[96 + c4_];          \
      xk[0] = Kv[c4_];      xk[1] = Kv[32 + c4_];          \
      xk[2] = Kv[64 + c4_]; xk[3] = Kv[96 + c4_]; }
#define FM(w0, w1, w2, w3, xq, xk)                         \
    fma4(acc[0], xq[0], w0, w1, w2, w3);                   \
    fma4(acc[1], xq[1], w0, w1, w2, w3);                   \
    fma4(acc[2], xq[2], w0, w1, w2, w3);                   \
    fma4(acc[3], xq[3], w0, w1, w2, w3);                   \
    fma4(acc[4], xk[0], w0, w1, w2, w3);                   \
    fma4(acc[5], xk[1], w0, w1, w2, w3);                   \
    fma4(acc[6], xk[2], w0, w1, w2, w3);                   \
    fma4(acc[7], xk[3], w0, w1, w2, w3);

    {
        float4 wA0, wA1, wA2, wA3, wB0, wB1, wB2, wB3;
        float4 xqA[4], xkA[4], xqB[4], xkB[4];

        LW(wA0, wA1, wA2, wA3, 0)
        LX(xqA, xkA, 0)
        for (int c = 0; c <= CC - 16; c += 8) {
            LW(wB0, wB1, wB2, wB3, c + 4)
            LX(xqB, xkB, c + 4)
            FM(wA0, wA1, wA2, wA3, xqA, xkA)
            LW(wA0, wA1, wA2, wA3, c + 8)
            LX(xqA, xkA, c + 8)
            FM(wB0, wB1, wB2, wB3, xqB, xkB)
        }
        LW(wB0, wB1, wB2, wB3, CC - 4)
        LX(xqB, xkB, CC - 4)
        FM(wA0, wA1, wA2, wA3, xqA, xkA)
        FM(wB0, wB1, wB2, wB3, xqB, xkB)
    }
#undef LW
#undef LX
#undef FM

    // q rows: store projected row + norm
#pragma unroll
    for (int i = 0; i < 4; i++) {
        const int rq = base + rg * 4 + i;
        float ss = acc[i].x * acc[i].x + acc[i].y * acc[i].y
                 + acc[i].z * acc[i].z + acc[i].w * acc[i].w;
#pragma unroll
        for (int off = 16; off > 0; off >>= 1) ss += __shfl_xor(ss, off, 32);
        ((float4*)(ws + QP_OFF + (size_t)rq * CC))[dg] = acc[i];
        if (dg == 0) ws[QN_OFF + rq] = sqrtf(ss);
    }

    __syncthreads();   // everyone done reading W before LDS reuse

    float* Khs = S;            // 64 x 128 (32 KB)
    float* Vs  = S + 8192;     // 64 x 128 (32 KB)

    // k rows: normalize into LDS
#pragma unroll
    for (int i = 0; i < 4; i++) {
        float ss = acc[4 + i].x * acc[4 + i].x + acc[4 + i].y * acc[4 + i].y
                 + acc[4 + i].z * acc[4 + i].z + acc[4 + i].w * acc[4 + i].w;
#pragma unroll
        for (int off = 16; off > 0; off >>= 1) ss += __shfl_xor(ss, off, 32);
        float inv = 1.0f / sqrtf(ss);
        float4 o = acc[4 + i];
        o.x *= inv; o.y *= inv; o.z *= inv; o.w *= inv;
        ((float4*)(Khs + (rg * 4 + i) * CC))[dg] = o;
    }

    // stage v rows 64x128 (each thread 4 float4)
    const int c4v = tid & 31, nrv = tid >> 5;   // nrv 0..15
    const float* Vp = v_node + (size_t)base * CC;
#pragma unroll
    for (int i = 0; i < 4; i++) {
        int n = nrv + i * 16;
        ((float4*)(Vs + n * CC))[c4v] = ((const float4*)(Vp + (size_t)n * CC))[c4v];
    }
    __syncthreads();

    // partial ksum (column sums of khat)
    float4 ksum4 = make_float4(0.f, 0.f, 0.f, 0.f);
#pragma unroll
    for (int i = 0; i < 4; i++) {
        int n = nrv + i * 16;
        float4 kv = ((const float4*)(Khs + n * CC))[c4v];
        ksum4.x += kv.x; ksum4.y += kv.y; ksum4.z += kv.z; ksum4.w += kv.w;
    }

    // rank-64 outer product, software-pipelined over n
    const int dg2 = tid & 15, cg = tid >> 4;    // cg 0..31
    float a2[4][8];
#pragma unroll
    for (int i = 0; i < 4; i++)
#pragma unroll
        for (int j = 0; j < 8; j++) a2[i][j] = 0.f;

#define P2L(ka, va, vb, n)                                  \
    ka = *(const float4*)(Khs + (n) * CC + 4 * cg);         \
    va = *(const float4*)(Vs + (n) * CC + 4 * dg2);         \
    vb = *(const float4*)(Vs + (n) * CC + 64 + 4 * dg2);
#define P2F(ka, va, vb)                                     \
    {  float kc[4] = {ka.x, ka.y, ka.z, ka.w};              \
       float vd[8] = {va.x, va.y, va.z, va.w,               \
                      vb.x, vb.y, vb.z, vb.w};              \
       _Pragma("unroll")                                    \
       for (int i = 0; i < 4; i++)                          \
           { _Pragma("unroll")                              \
             for (int j = 0; j < 8; j++)                    \
                 a2[i][j] += kc[i] * vd[j]; } }

    {
        float4 kaA, vaA, vbA, kaB, vaB, vbB;
        P2L(kaA, vaA, vbA, 0)
        for (int n = 0; n <= 60; n += 2) {
            P2L(kaB, vaB, vbB, n + 1)
            P2F(kaA, vaA, vbA)
            P2L(kaA, vaA, vbA, n + 2)
            P2F(kaB, vaB, vbB)
        }
        P2L(kaB, vaB, vbB, 63)
        P2F(kaA, vaA, vbA)
        P2F(kaB, vaB, vbB)
    }
#undef P2L
#undef P2F

    float* pp = ws + PP_OFF + (size_t)blk * (CC * CC);
#pragma unroll
    for (int i = 0; i < 4; i++) {
        int c = 4 * cg + i;
        *(float4*)(pp + c * CC + 4 * dg2) =
            make_float4(a2[i][0], a2[i][1], a2[i][2], a2[i][3]);
        *(float4*)(pp + c * CC + 64 + 4 * dg2) =
            make_float4(a2[i][4], a2[i][5], a2[i][6], a2[i][7]);
    }

    red[nrv * 32 + c4v] = ksum4;
    __syncthreads();
    if (tid < 32) {
        float4 sm = red[tid];
#pragma unroll
        for (int i = 1; i < 16; i++) {
            float4 t = red[i * 32 + tid];
            sm.x += t.x; sm.y += t.y; sm.z += t.z; sm.w += t.w;
        }
        ((float4*)(ws + KP_OFF + (size_t)blk * CC))[tid] = sm;
    }
}

// ---------------------------------------------------------------------------
// Kernel 2: fused reduce + M-build (64 partials per batch now).
// ---------------------------------------------------------------------------
__global__ __launch_bounds__(256) void mchain_kernel(const float* __restrict__ W,
                                                     const float* __restrict__ bias,
                                                     float* __restrict__ ws)
{
    __shared__ float4 W4s[CC * 32];    // W natural, float4-swizzled per row
    __shared__ float m0row[2][CC];
    __shared__ float kpart[4];
    __shared__ float ksl[2];
    const int tid = threadIdx.x;
    const int b = blockIdx.y, x = blockIdx.x;
    const int c0 = x * 2;

    for (int idx = tid; idx < CC * 32; idx += 256) {
        int e = idx >> 5, d4 = idx & 31;
        W4s[(e << 5) + (d4 ^ (e & 31))] = ((const float4*)W)[idx];
    }

    // reduce 2 rows of M0 over 64 partials (each thread one element)
    {
        const int r = tid >> 7, d = tid & 127;
        const float* pp = ws + PP_OFF + (size_t)(b * 64) * (CC * CC)
                        + (size_t)(c0 + r) * CC + d;
        float a0 = 0.f, a1 = 0.f, a2 = 0.f, a3 = 0.f;
#pragma unroll 8
        for (int p = 0; p < 64; p += 4) {
            a0 += pp[(size_t)(p + 0) * (CC * CC)];
            a1 += pp[(size_t)(p + 1) * (CC * CC)];
            a2 += pp[(size_t)(p + 2) * (CC * CC)];
            a3 += pp[(size_t)(p + 3) * (CC * CC)];
        }
        m0row[r][d] = (a0 + a1) + (a2 + a3);
    }

    // reduce 2 Ksum entries over 64 partials
    {
        const int rr = tid >> 7, p = tid & 127;
        float v = 0.f;
        if (p < 64) v = ws[KP_OFF + (size_t)(b * 64 + p) * CC + c0 + rr];
#pragma unroll
        for (int off = 32; off > 0; off >>= 1) v += __shfl_xor(v, off, 64);
        if ((tid & 63) == 0) kpart[tid >> 6] = v;
    }
    __syncthreads();
    if (tid < 2) {
        float s = kpart[tid * 2] + kpart[tid * 2 + 1];
        ksl[tid] = s;
        ws[KS_OFF + b * CC + c0 + tid] = s;
    }
    __syncthreads();

    // M = M0 @ W^T + Ksum b^T  (thread -> one output element)
    const int r = tid >> 7, e = tid & 127;
    const float4* mr = (const float4*)m0row[r];
    float m = 0.f;
#pragma unroll
    for (int d4 = 0; d4 < 32; d4++) {
        float4 a4 = mr[d4];                              // broadcast
        float4 w4 = W4s[(e << 5) + (d4 ^ (e & 31))];     // conflict-spread
        m += a4.x * w4.x + a4.y * w4.y + a4.z * w4.z + a4.w * w4.w;
    }
    m += ksl[r] * bias[e];
    ws[MM_OFF + (size_t)b * CC * CC + (size_t)(c0 + r) * CC + e] = m;
}

// ---------------------------------------------------------------------------
// Kernel 3: out[b,r,:] = (q_proj[r] @ M) / (q_proj[r].Ksum + 1e-8*|q_proj[r]|)
// 256 blocks x 512 threads, 64 rows per block, 4 row-accs per thread,
// software-pipelined c-loop.
// ---------------------------------------------------------------------------
__global__ __launch_bounds__(512, 2) void out_kernel(const float* __restrict__ ws,
                                                     float* __restrict__ out)
{
    __shared__ float Ml[CC * CC];

    const int blk = blockIdx.x;     // 0..255
    const int b = blk >> 6;
    const int r0 = (blk & 63) * 64;
    const float* M = ws + MM_OFF + (size_t)b * CC * CC;
    const int tid = threadIdx.x;

    for (int e = tid; e < CC * CC / 4; e += 512)
        ((float4*)Ml)[e] = ((const float4*)M)[e];

    const float4* Ks4 = (const float4*)(ws + KS_OFF + b * CC);
    const int dg = tid & 31, rg = tid >> 5;   // rg 0..15, 4 rows each
    const int row = r0 + rg * 4;
    const float4* Qv = (const float4*)(ws + QP_OFF + ((size_t)b * NN + row) * CC);
    const float4* Mv = (const float4*)Ml;

    float4 acc[4];
    float s[4];
#pragma unroll
    for (int i = 0; i < 4; i++) {
        acc[i] = make_float4(0.f, 0.f, 0.f, 0.f);
        s[i] = 0.f;
    }

    __syncthreads();

#define OLW(m0, m1, m2, m3, ks, c)               \
    m0 = Mv[(((c) + 0) << 5) + dg];              \
    m1 = Mv[(((c) + 1) << 5) + dg];              \
    m2 = Mv[(((c) + 2) << 5) + dg];              \
    m3 = Mv[(((c) + 3) << 5) + dg];              \
    ks = Ks4[(c) >> 2];
#define OLX(xv, c)                                 \
    { const int c4_ = (c) >> 2;                    \
      xv[0] = Qv[c4_];      xv[1] = Qv[32 + c4_];  \
      xv[2] = Qv[64 + c4_]; xv[3] = Qv[96 + c4_]; }
#define OFM(m0, m1, m2, m3, ks, xv)                  \
    _Pragma("unroll")                                \
    for (int i_ = 0; i_ < 4; i_++) {                 \
        fma4(acc[i_], xv[i_], m0, m1, m2, m3);       \
        s[i_] += dot4(xv[i_], ks);                   \
    }

    {
        float4 mA0, mA1, mA2, mA3, mB0, mB1, mB2, mB3;
        float4 ksA, ksB, xA[4], xB[4];
        OLW(mA0, mA1, mA2, mA3, ksA, 0)
        OLX(xA, 0)
        for (int c = 0; c <= CC - 16; c += 8) {
            OLW(mB0, mB1, mB2, mB3, ksB, c + 4)
            OLX(xB, c + 4)
            OFM(mA0, mA1, mA2, mA3, ksA, xA)
            OLW(mA0, mA1, mA2, mA3, ksA, c + 8)
            OLX(xA, c + 8)
            OFM(mB0, mB1, mB2, mB3, ksB, xB)
        }
        OLW(mB0, mB1, mB2, mB3, ksB, CC - 4)
        OLX(xB, CC - 4)
        OFM(mA0, mA1, mA2, mA3, ksA, xA)
        OFM(mB0, mB1, mB2, mB3, ksB, xB)
    }
#undef OLW
#undef OLX
#undef OFM

    float* op = out + ((size_t)b * NN + row) * CC;
    const float* qn = ws + QN_OFF + (size_t)b * NN + row;
#pragma unroll
    for (int i = 0; i < 4; i++) {
        float inv = 1.0f / (s[i] + 1e-8f * qn[i]);
        float4 o = acc[i];
        o.x *= inv; o.y *= inv; o.z *= inv; o.w *= inv;
        ((float4*)(op + (size_t)i * CC))[dg] = o;
    }
}

// ---------------------------------------------------------------------------
extern "C" void kernel_launch(void* const* d_in, const int* in_sizes, int n_in,
                              void* d_out, int out_size, void* d_ws, size_t ws_size,
                              hipStream_t stream)
{
    const float* q_node = (const float*)d_in[0];
    const float* k_node = (const float*)d_in[1];
    const float* v_node = (const float*)d_in[2];
    const float* W      = (const float*)d_in[3];
    const float* bias   = (const float*)d_in[4];
    float* out = (float*)d_out;
    float* ws  = (float*)d_ws;

    projpb_kernel<<<256, 512, 0, stream>>>(q_node, k_node, v_node, W, bias, ws);
    mchain_kernel<<<dim3(64, BB), 256, 0, stream>>>(W, bias, ws);
    out_kernel<<<256, 512, 0, stream>>>(ws, out);
}